// Round 1
// baseline (192.866 us; speedup 1.0000x reference)
//
#include <hip/hip_runtime.h>
#include <math.h>

#define NB 64
#define NC 1000
#define ND 2048

// ws layout (float offsets), total ~16.8 MB
enum : int {
  WS_XT    = 0,         // [2048][64] x transposed
  WS_X2P   = 131072,    // [32][64] partial sums of x^2
  WS_C2    = 133120,    // [1000]
  WS_CWRN  = 134120,    // [1000] 1/||cos_w row||
  WS_D2MIN = 135120,    // [64] uint bits
  WS_P12   = 135184,    // [8][2048][64] partials: c<1000 centers-dot, else fc1-dot
  WS_P3    = 1183760,   // [8][2048][64] partials fc_channel
  WS_L1T   = 2232336,   // [1000][64]
  WS_PROBT = 2296336,   // [1000][64]
  WS_CONF  = 2360336,   // [64]
  WS_SELT  = 2360400,   // [2048][64] channel selector transposed
  WS_P4    = 2491472,   // [8][64][2048] partials prob@centers
  WS_XNT   = 3540048,   // [2048][64] x_new transposed
  WS_XN2P  = 3671120,   // [32][64] partial sums of x_new^2
  WS_P5    = 3673168,   // [8][1024][64]
};

// ---- K_A: per-class stats (c2, 1/||cos_w||) + x transpose + x^2 partials + d2min init
__global__ __launch_bounds__(256) void kA(const float* __restrict__ x,
                                          const float* __restrict__ centers,
                                          const float* __restrict__ cosw,
                                          float* __restrict__ ws) {
  int blk = blockIdx.x, t = threadIdx.x;
  if (blk < 250) {
    int lane = t & 63, wid = t >> 6;
    int c = blk * 4 + wid;
    const float4* cr = (const float4*)(centers + (size_t)c * ND);
    const float4* wr = (const float4*)(cosw + (size_t)c * ND);
    float s1 = 0.f, s2 = 0.f;
#pragma unroll
    for (int i = 0; i < 8; ++i) {
      float4 a = cr[lane + 64 * i];
      float4 b = wr[lane + 64 * i];
      s1 += a.x * a.x + a.y * a.y + a.z * a.z + a.w * a.w;
      s2 += b.x * b.x + b.y * b.y + b.z * b.z + b.w * b.w;
    }
#pragma unroll
    for (int o = 32; o > 0; o >>= 1) {
      s1 += __shfl_xor(s1, o);
      s2 += __shfl_xor(s2, o);
    }
    if (lane == 0) {
      ws[WS_C2 + c] = s1;
      ws[WS_CWRN + c] = 1.0f / sqrtf(s2);
    }
    if (blk == 0 && t < 64) ((unsigned*)(ws + WS_D2MIN))[t] = 0x7f800000u;  // +inf
  } else {
    __shared__ float A[64][65];
    int kb = blk - 250;  // 0..31
    int k0 = kb * 64;
    int lane = t & 63, rr = t >> 6;
#pragma unroll
    for (int r = 0; r < 16; ++r) {
      int b = rr + r * 4;
      A[b][lane] = x[b * ND + k0 + lane];
    }
    __syncthreads();
#pragma unroll
    for (int r = 0; r < 16; ++r) {
      int k = rr + r * 4;
      ws[WS_XT + (k0 + k) * 64 + lane] = A[lane][k];
    }
    if (t < 64) {
      float s = 0.f;
#pragma unroll
      for (int k = 0; k < 64; ++k) { float v = A[t][k]; s += v * v; }
      ws[WS_X2P + kb * 64 + t] = s;
    }
  }
}

// ---- K_B: broadcast split-K GEMM partials for GEMM1 (x@centers^T), GEMM2 (x@fc1^T),
//           GEMM3 (x@fc_channel^T). lane=b, xT chunk in LDS, W rows via uniform loads.
__global__ __launch_bounds__(256) void kB(const float* __restrict__ centers,
                                          const float* __restrict__ fc1w,
                                          const float* __restrict__ fcw,
                                          float* __restrict__ ws) {
  __shared__ float xs[256 * 64];  // 64 KB
  int blk = blockIdx.x, t = threadIdx.x;
  int lane = t & 63, wid = t >> 6;
  int which, cgrp, j;
  if (blk < 504) { which = 0; cgrp = blk >> 3; j = blk & 7; }
  else           { which = 1; int bb = blk - 504; cgrp = bb >> 3; j = bb & 7; }
  int k0 = j * 256;

  const float4* src = (const float4*)(ws + WS_XT + k0 * 64);
  float4* dst = (float4*)xs;
#pragma unroll
  for (int i = 0; i < 16; ++i) dst[t + 256 * i] = src[t + 256 * i];
  __syncthreads();

  int cbase = __builtin_amdgcn_readfirstlane(cgrp * 32 + wid * 8);
  const float* rows[8];
#pragma unroll
  for (int cc = 0; cc < 8; ++cc) {
    int c = cbase + cc;
    const float* r;
    if (which == 0) {
      if (c < 1000)      r = centers + (size_t)c * ND;
      else if (c < 2000) r = fc1w + (size_t)(c - 1000) * ND;
      else               r = centers;  // guarded, not stored
    } else {
      r = fcw + (size_t)c * ND;  // c < 2048 always
    }
    rows[cc] = r + k0;
  }

  float acc[8] = {0.f, 0.f, 0.f, 0.f, 0.f, 0.f, 0.f, 0.f};
  for (int kk = 0; kk < 256; kk += 4) {
    float a0 = xs[(kk + 0) * 64 + lane];
    float a1 = xs[(kk + 1) * 64 + lane];
    float a2 = xs[(kk + 2) * 64 + lane];
    float a3 = xs[(kk + 3) * 64 + lane];
#pragma unroll
    for (int cc = 0; cc < 8; ++cc) {
      float4 w = *(const float4*)(rows[cc] + kk);
      acc[cc] += a0 * w.x + a1 * w.y + a2 * w.z + a3 * w.w;
    }
  }

  float* pout = ws + (which == 0 ? WS_P12 : WS_P3);
#pragma unroll
  for (int cc = 0; cc < 8; ++cc) {
    int c = cbase + cc;
    if (which == 0 && c >= 2000) continue;
    pout[((size_t)j * 2048 + c) * 64 + lane] = acc[cc];
  }
}

// ---- K_R: reduce split-K partials. blocks<500: GEMM12 -> d2min(atomicMin)/L1T.
//           blocks>=500: GEMM3 -> selector^T (tanh).
__global__ __launch_bounds__(256) void kR(const float* __restrict__ fc1b,
                                          const float* __restrict__ fcb,
                                          float* __restrict__ ws) {
  __shared__ float sh[64];
  __shared__ float dt[4][64];
  int blk = blockIdx.x, t = threadIdx.x;
  int b = t & 63, ci = t >> 6;
  if (blk < 500) {
    int c = blk * 4 + ci;  // 0..1999
    if (blk < 250) {       // need x2 for the d2 branch
      if (t < 64) {
        float s = 0.f;
        for (int jj = 0; jj < 32; ++jj) s += ws[WS_X2P + jj * 64 + t];
        sh[t] = s;
      }
      __syncthreads();
    }
    float s = 0.f;
#pragma unroll
    for (int j = 0; j < 8; ++j) s += ws[WS_P12 + ((size_t)j * 2048 + c) * 64 + b];
    if (c < 1000) {
      float d2 = fmaxf(sh[b] - 2.f * s + ws[WS_C2 + c], 0.f);
      dt[ci][b] = d2;
      __syncthreads();
      if (t < 64) {
        float m = fminf(fminf(dt[0][t], dt[1][t]), fminf(dt[2][t], dt[3][t]));
        atomicMin((unsigned*)(ws + WS_D2MIN) + t, __float_as_uint(m));
      }
    } else {
      ws[WS_L1T + (size_t)(c - 1000) * 64 + b] = s + fc1b[c - 1000];
    }
  } else {
    int d = (blk - 500) * 4 + ci;  // 0..2047
    float s = 0.f;
#pragma unroll
    for (int j = 0; j < 8; ++j) s += ws[WS_P3 + ((size_t)j * 2048 + d) * 64 + b];
    ws[WS_SELT + (size_t)d * 64 + b] = tanhf(s + fcb[d]);
  }
}

// ---- K_C: confidence + row softmax over L1T (lane=b, column-parallel, no shuffles)
__global__ __launch_bounds__(256) void kC(float* __restrict__ ws) {
  __shared__ float red[4][64];
  __shared__ float Mv[64], Sv[64];
  int t = threadIdx.x, lane = t & 63, wid = t >> 6;
  if (t < 64) {
    float d2 = __uint_as_float(((unsigned*)(ws + WS_D2MIN))[t]);
    ws[WS_CONF + t] = 10.0f / sqrtf(d2);
  }
  int c0 = wid * 250, c1 = c0 + 250;
  float m = -3.0e38f;
  for (int c = c0; c < c1; ++c) m = fmaxf(m, ws[WS_L1T + c * 64 + lane]);
  red[wid][lane] = m;
  __syncthreads();
  if (t < 64) Mv[t] = fmaxf(fmaxf(red[0][t], red[1][t]), fmaxf(red[2][t], red[3][t]));
  __syncthreads();
  float M = Mv[lane];
  float s = 0.f;
  for (int c = c0; c < c1; ++c) s += __expf(ws[WS_L1T + c * 64 + lane] - M);
  red[wid][lane] = s;
  __syncthreads();
  if (t < 64) Sv[t] = 1.0f / (red[0][t] + red[1][t] + red[2][t] + red[3][t]);
  __syncthreads();
  float Si = Sv[lane];
  for (int c = c0; c < c1; ++c)
    ws[WS_PROBT + c * 64 + lane] = __expf(ws[WS_L1T + c * 64 + lane] - M) * Si;
}

// ---- K_D: centers_cur partials = prob @ centers (lane=d, prob via uniform loads)
__global__ __launch_bounds__(256) void kD(const float* __restrict__ centers,
                                          float* __restrict__ ws) {
  int blk = blockIdx.x, t = threadIdx.x;
  int lane = t & 63, wid = t >> 6;
  int dg = blk & 31, j = blk >> 5;  // 32 d-groups x 8 c-splits
  int d0 = dg * 64;
  int c0 = j * 125, c1 = c0 + 125;
  int b0 = __builtin_amdgcn_readfirstlane(wid * 16);
  float acc[16];
#pragma unroll
  for (int i = 0; i < 16; ++i) acc[i] = 0.f;
  for (int c = c0; c < c1; ++c) {
    float v = centers[(size_t)c * ND + d0 + lane];
    const float* pr = ws + WS_PROBT + c * 64 + b0;
#pragma unroll
    for (int i = 0; i < 16; ++i) acc[i] += v * pr[i];
  }
#pragma unroll
  for (int i = 0; i < 16; ++i)
    ws[WS_P4 + ((size_t)j * 64 + b0 + i) * 2048 + d0 + lane] = acc[i];
}

// ---- K_F: elementwise fuse: centers_cur reduce, fast/slow outputs, x_new,
//           x_new transpose, x_new^2 partials
__global__ __launch_bounds__(256) void kF(const float* __restrict__ x,
                                          float* __restrict__ out,
                                          float* __restrict__ ws) {
  __shared__ float Sel[64][65];
  __shared__ float T[64][65];
  int blk = blockIdx.x, t = threadIdx.x;
  int lane = t & 63, rr = t >> 6;
  int d0 = blk * 64;
#pragma unroll
  for (int r = 0; r < 16; ++r) {
    int dl = rr + r * 4;
    Sel[dl][lane] = ws[WS_SELT + (size_t)(d0 + dl) * 64 + lane];
  }
  __syncthreads();
#pragma unroll
  for (int r = 0; r < 16; ++r) {
    int b = rr + r * 4;
    float xv = x[b * ND + d0 + lane];
    float cc = 0.f;
#pragma unroll
    for (int j = 0; j < 8; ++j) cc += ws[WS_P4 + ((size_t)j * 64 + b) * 2048 + d0 + lane];
    float sel = Sel[lane][b];
    float fast = sel * cc;
    float xn = ws[WS_CONF + b] * (xv + fast);
    out[64000 + b * ND + d0 + lane] = xv;     // slow_feature
    out[195072 + b * ND + d0 + lane] = fast;  // fast_feature
    T[b][lane] = xn;
  }
  __syncthreads();
#pragma unroll
  for (int r = 0; r < 16; ++r) {
    int dl = rr + r * 4;
    ws[WS_XNT + (size_t)(d0 + dl) * 64 + lane] = T[lane][dl];
  }
  if (t < 64) {
    float s = 0.f;
#pragma unroll
    for (int k = 0; k < 64; ++k) { float v = T[t][k]; s += v * v; }
    ws[WS_XN2P + blk * 64 + t] = s;
  }
}

// ---- K_G: cos logits partials = x_new @ cos_w^T (broadcast pattern, split-K)
__global__ __launch_bounds__(256) void kG(const float* __restrict__ cosw,
                                          float* __restrict__ ws) {
  __shared__ float xs[256 * 64];
  int blk = blockIdx.x, t = threadIdx.x;
  int lane = t & 63, wid = t >> 6;
  int cgrp = blk >> 3, j = blk & 7;
  int k0 = j * 256;
  const float4* src = (const float4*)(ws + WS_XNT + k0 * 64);
  float4* dst = (float4*)xs;
#pragma unroll
  for (int i = 0; i < 16; ++i) dst[t + 256 * i] = src[t + 256 * i];
  __syncthreads();
  int cbase = __builtin_amdgcn_readfirstlane(cgrp * 32 + wid * 8);
  const float* rows[8];
#pragma unroll
  for (int cc = 0; cc < 8; ++cc) {
    int c = cbase + cc;
    rows[cc] = cosw + (size_t)(c < 1000 ? c : 999) * ND + k0;
  }
  float acc[8] = {0.f, 0.f, 0.f, 0.f, 0.f, 0.f, 0.f, 0.f};
  for (int kk = 0; kk < 256; kk += 4) {
    float a0 = xs[(kk + 0) * 64 + lane];
    float a1 = xs[(kk + 1) * 64 + lane];
    float a2 = xs[(kk + 2) * 64 + lane];
    float a3 = xs[(kk + 3) * 64 + lane];
#pragma unroll
    for (int cc = 0; cc < 8; ++cc) {
      float4 w = *(const float4*)(rows[cc] + kk);
      acc[cc] += a0 * w.x + a1 * w.y + a2 * w.z + a3 * w.w;
    }
  }
#pragma unroll
  for (int cc = 0; cc < 8; ++cc) {
    int c = cbase + cc;
    if (c < 1000) ws[WS_P5 + ((size_t)j * 1024 + c) * 64 + lane] = acc[cc];
  }
}

// ---- K_H: reduce GEMM5 + CosNorm scaling + transposed coalesced write of logits
__global__ __launch_bounds__(256) void kH(float* __restrict__ out,
                                          const float* __restrict__ ws) {
  __shared__ float nrm[64];
  __shared__ float tile[64][65];
  int blk = blockIdx.x, t = threadIdx.x;
  int lane = t & 63, rr = t >> 6;
  int c0 = blk * 64;
  if (t < 64) {
    float s = 0.f;
    for (int jj = 0; jj < 32; ++jj) s += ws[WS_XN2P + jj * 64 + t];
    nrm[t] = sqrtf(s);
  }
  __syncthreads();
#pragma unroll
  for (int r = 0; r < 16; ++r) {
    int cl = rr + r * 4;
    int c = c0 + cl;
    float lg = 0.f;
    if (c < 1000) {
      float s = 0.f;
#pragma unroll
      for (int j = 0; j < 8; ++j) s += ws[WS_P5 + ((size_t)j * 1024 + c) * 64 + lane];
      lg = 16.0f * s * ws[WS_CWRN + c] / (1.0f + nrm[lane]);
    }
    tile[lane][cl] = lg;  // tile[b][c_local]
  }
  __syncthreads();
#pragma unroll
  for (int r = 0; r < 16; ++r) {
    int b = rr + r * 4;
    int c = c0 + lane;
    if (c < 1000) out[b * 1000 + c] = tile[b][lane];
  }
}

extern "C" void kernel_launch(void* const* d_in, const int* in_sizes, int n_in,
                              void* d_out, int out_size, void* d_ws, size_t ws_size,
                              hipStream_t stream) {
  const float* x       = (const float*)d_in[0];
  const float* centers = (const float*)d_in[2];
  const float* fcw     = (const float*)d_in[4];
  const float* fcb     = (const float*)d_in[5];
  const float* fc1w    = (const float*)d_in[6];
  const float* fc1b    = (const float*)d_in[7];
  const float* cosw    = (const float*)d_in[8];
  float* out = (float*)d_out;
  float* ws  = (float*)d_ws;

  hipLaunchKernelGGL(kA, dim3(282), dim3(256), 0, stream, x, centers, cosw, ws);
  hipLaunchKernelGGL(kB, dim3(1016), dim3(256), 0, stream, centers, fc1w, fcw, ws);
  hipLaunchKernelGGL(kR, dim3(1012), dim3(256), 0, stream, fc1b, fcb, ws);
  hipLaunchKernelGGL(kC, dim3(1), dim3(256), 0, stream, ws);
  hipLaunchKernelGGL(kD, dim3(256), dim3(256), 0, stream, centers, ws);
  hipLaunchKernelGGL(kF, dim3(32), dim3(256), 0, stream, x, out, ws);
  hipLaunchKernelGGL(kG, dim3(256), dim3(256), 0, stream, cosw, ws);
  hipLaunchKernelGGL(kH, dim3(16), dim3(256), 0, stream, out, ws);
}

// Round 2
// 79.431 us; speedup vs baseline: 2.4281x; 2.4281x over previous
//
#include <hip/hip_runtime.h>
#include <hip/hip_bf16.h>
#include <math.h>

typedef __attribute__((ext_vector_type(8))) short short8;
typedef __attribute__((ext_vector_type(4))) float f32x4;

#define MFMA(a, b, c) __builtin_amdgcn_mfma_f32_16x16x32_bf16(a, b, c, 0, 0, 0)

// ws layout (float offsets)
enum : int {
  WS_XB   = 0,        // [64][2048] bf16 (ushort view)           65536 floats
  WS_X2   = 65536,    // [64] f32 row sumsq of x
  WS_D2MIN= 65600,    // [64] uint bits
  WS_CONF = 65664,    // [64]
  WS_P123 = 65728,    // [4][4096][68] f32 partials (+[64]=sumsq) 1114112
  WS_L1   = 1179840,  // [64][1024] f32 row-major logits_stage1
  WS_PROB = 1245376,  // [64][1024] bf16 (ushort view)
  WS_SEL  = 1278144,  // [64][2048] bf16 (ushort view)
  WS_P4   = 1343680,  // [4][2048][68] f32 partials               557056
  WS_XNB  = 1900736,  // [64][2048] bf16 (ushort view)
  WS_XN2P = 1966272,  // [32][64] f32 partials of ||x_new||^2
  WS_P5   = 1968320,  // [4][1024][68] f32 partials (+sumsq)      278528
};

__device__ inline short bfs(float f) {
  __hip_bfloat16 h = __float2bfloat16(f);
  return __builtin_bit_cast(short, h);
}
__device__ inline float bf2f(unsigned short u) {
  return __uint_as_float((unsigned)u << 16);
}

// ---- K1: x -> bf16, x row sumsq, slow_feature out, d2min init
__global__ __launch_bounds__(256) void k1(const float* __restrict__ x,
                                          float* __restrict__ out,
                                          float* __restrict__ ws) {
  __shared__ float red[4];
  int b = blockIdx.x, t = threadIdx.x;
  int l = t & 63, w = t >> 6;
  const float* xr = x + (size_t)b * 2048 + t * 8;
  float4 f0 = *(const float4*)(xr);
  float4 f1 = *(const float4*)(xr + 4);
  short8 h;
  h[0] = bfs(f0.x); h[1] = bfs(f0.y); h[2] = bfs(f0.z); h[3] = bfs(f0.w);
  h[4] = bfs(f1.x); h[5] = bfs(f1.y); h[6] = bfs(f1.z); h[7] = bfs(f1.w);
  *(short8*)((unsigned short*)(ws + WS_XB) + (size_t)b * 2048 + t * 8) = h;
  *(float4*)(out + 64000 + (size_t)b * 2048 + t * 8) = f0;
  *(float4*)(out + 64000 + (size_t)b * 2048 + t * 8 + 4) = f1;
  float s = f0.x*f0.x + f0.y*f0.y + f0.z*f0.z + f0.w*f0.w
          + f1.x*f1.x + f1.y*f1.y + f1.z*f1.z + f1.w*f1.w;
#pragma unroll
  for (int o = 32; o; o >>= 1) s += __shfl_xor(s, o);
  if (l == 0) red[w] = s;
  __syncthreads();
  if (t == 0) ws[WS_X2 + b] = red[0] + red[1] + red[2] + red[3];
  if (b == 0 && t < 64) ((unsigned*)(ws + WS_D2MIN))[t] = 0x7f800000u;  // +inf
}

// ---- K2: fused G1/G2/G3 = x @ [centers; fc1w; fcw]^T via MFMA, split-K=4
// grid 512 = 128 colblks x 4 ksplit; 4 waves: (w&1)=col half, (w>>1)=m half
__global__ __launch_bounds__(256) void k2(const float* __restrict__ centers,
                                          const float* __restrict__ fc1w,
                                          const float* __restrict__ fcw,
                                          float* __restrict__ ws) {
  int blk = blockIdx.x, t = threadIdx.x;
  int w = t >> 6, l = t & 63;
  int colblk = blk & 127, ksplit = blk >> 7;
  int ln = l & 15, lk = l >> 4;
  int n = colblk * 32 + (w & 1) * 16 + ln;   // 0..4095
  int m0 = (w >> 1) * 32;
  int k0 = ksplit * 512;
  const float* brow;
  if (n < 1024)      brow = centers + (size_t)min(n, 999) * 2048;
  else if (n < 2048) brow = fc1w + (size_t)min(n - 1024, 999) * 2048;
  else               brow = fcw + (size_t)(n - 2048) * 2048;
  const float* bptr = brow + k0 + lk * 8;
  const unsigned short* aptr =
      (const unsigned short*)(ws + WS_XB) + (size_t)(m0 + ln) * 2048 + k0 + lk * 8;
  f32x4 acc0 = {0.f, 0.f, 0.f, 0.f}, acc1 = {0.f, 0.f, 0.f, 0.f};
  float sq = 0.f;
#pragma unroll 4
  for (int ks = 0; ks < 16; ++ks) {
    short8 a0 = *(const short8*)(aptr + ks * 32);
    short8 a1 = *(const short8*)(aptr + 16 * 2048 + ks * 32);
    float4 f0 = *(const float4*)(bptr + ks * 32);
    float4 f1 = *(const float4*)(bptr + ks * 32 + 4);
    sq += f0.x*f0.x + f0.y*f0.y + f0.z*f0.z + f0.w*f0.w
        + f1.x*f1.x + f1.y*f1.y + f1.z*f1.z + f1.w*f1.w;
    short8 bb;
    bb[0] = bfs(f0.x); bb[1] = bfs(f0.y); bb[2] = bfs(f0.z); bb[3] = bfs(f0.w);
    bb[4] = bfs(f1.x); bb[5] = bfs(f1.y); bb[6] = bfs(f1.z); bb[7] = bfs(f1.w);
    acc0 = MFMA(a0, bb, acc0);
    acc1 = MFMA(a1, bb, acc1);
  }
  float* P = ws + WS_P123 + ((size_t)ksplit * 4096 + n) * 68;
  *(f32x4*)(P + m0 + lk * 4) = acc0;
  *(f32x4*)(P + m0 + 16 + lk * 4) = acc1;
  sq += __shfl_xor(sq, 16);
  sq += __shfl_xor(sq, 32);
  if (w < 2 && l < 16) P[64] = sq;   // per-col ||w||^2 partial
}

// ---- K3: reduce P123 -> d2min (seg A) / L1 (seg B) / SEL=tanh (seg C)
__global__ __launch_bounds__(256) void k3(const float* __restrict__ fc1b,
                                          const float* __restrict__ fcb,
                                          float* __restrict__ ws) {
  __shared__ float tile[64][65];
  __shared__ float red[4][64];
  int blk = blockIdx.x, t = threadIdx.x;
  int l = t & 63, w = t >> 6;
  int n0 = blk * 64;
  const size_t KS = (size_t)4096 * 68;
  float x2 = ws[WS_X2 + l];
  float tmin = 3.0e38f;
  for (int nl = w; nl < 64; nl += 4) {
    int n = n0 + nl;
    const float* P = ws + WS_P123 + (size_t)n * 68;
    float v = P[l] + P[KS + l] + P[2*KS + l] + P[3*KS + l];
    if (n < 1024) {
      if (n < 1000) {
        float c2 = P[64] + P[KS+64] + P[2*KS+64] + P[3*KS+64];
        float d2 = fmaxf(x2 - 2.f * v + c2, 0.f);
        tmin = fminf(tmin, d2);
      }
    } else if (n < 2048) {
      int c = n - 1024;
      tile[nl][l] = (c < 1000) ? v + fc1b[c] : 0.f;
    } else {
      tile[nl][l] = tanhf(v + fcb[n - 2048]);
    }
  }
  if (n0 < 1024) {
    red[w][l] = tmin;
    __syncthreads();
    if (t < 64) {
      float m = fminf(fminf(red[0][t], red[1][t]), fminf(red[2][t], red[3][t]));
      atomicMin((unsigned*)(ws + WS_D2MIN) + t, __float_as_uint(m));
    }
  } else if (n0 < 2048) {
    __syncthreads();
    int c0 = n0 - 1024;
    for (int r = 0; r < 16; ++r) {
      int m = w * 16 + r;
      ws[WS_L1 + (size_t)m * 1024 + c0 + l] = tile[l][m];
    }
  } else {
    __syncthreads();
    int d0 = n0 - 2048;
    unsigned short* sel = (unsigned short*)(ws + WS_SEL);
    for (int r = 0; r < 16; ++r) {
      int m = w * 16 + r;
      sel[(size_t)m * 2048 + d0 + l] = (unsigned short)bfs(tile[l][m]);
    }
  }
}

// ---- K4: confidence + row softmax -> PROB bf16 (wave per row)
__global__ __launch_bounds__(256) void k4(float* __restrict__ ws) {
  int t = threadIdx.x, l = t & 63, w = t >> 6;
  int b = blockIdx.x * 4 + w;
  if (blockIdx.x == 0 && t < 64) {
    float d2 = __uint_as_float(((unsigned*)(ws + WS_D2MIN))[t]);
    ws[WS_CONF + t] = 10.0f / sqrtf(d2);
  }
  const float* L = ws + WS_L1 + (size_t)b * 1024;
  float vals[16];
  float m = -3.0e38f;
#pragma unroll
  for (int i = 0; i < 16; ++i) {
    int c = i * 64 + l;
    float v = (c < 1000) ? L[c] : -3.0e38f;
    vals[i] = v;
    m = fmaxf(m, v);
  }
#pragma unroll
  for (int o = 32; o; o >>= 1) m = fmaxf(m, __shfl_xor(m, o));
  float s = 0.f;
#pragma unroll
  for (int i = 0; i < 16; ++i) {
    float e = (vals[i] > -1.0e37f) ? __expf(vals[i] - m) : 0.f;
    vals[i] = e;
    s += e;
  }
#pragma unroll
  for (int o = 32; o; o >>= 1) s += __shfl_xor(s, o);
  float inv = 1.0f / s;
  unsigned short* pb = (unsigned short*)(ws + WS_PROB) + (size_t)b * 1024;
#pragma unroll
  for (int i = 0; i < 16; ++i) pb[i * 64 + l] = (unsigned short)bfs(vals[i] * inv);
}

// ---- K5: G4 = prob @ centers (B is non-transposed: B[k][n]=centers[c][d])
// grid 256 = 64 colblks x 4 ksplit (K=1024 padded; prob[c>=1000]=0)
__global__ __launch_bounds__(256) void k5(const float* __restrict__ centers,
                                          float* __restrict__ ws) {
  int blk = blockIdx.x, t = threadIdx.x;
  int w = t >> 6, l = t & 63;
  int colblk = blk & 63, ksplit = blk >> 6;
  int ln = l & 15, lk = l >> 4;
  int n = colblk * 32 + (w & 1) * 16 + ln;   // d: 0..2047
  int m0 = (w >> 1) * 32;
  int k0 = ksplit * 256;
  const unsigned short* aptr =
      (const unsigned short*)(ws + WS_PROB) + (size_t)(m0 + ln) * 1024 + k0 + lk * 8;
  f32x4 acc0 = {0.f, 0.f, 0.f, 0.f}, acc1 = {0.f, 0.f, 0.f, 0.f};
  for (int ks = 0; ks < 8; ++ks) {
    short8 a0 = *(const short8*)(aptr + ks * 32);
    short8 a1 = *(const short8*)(aptr + 16 * 1024 + ks * 32);
    int kbase = k0 + ks * 32 + lk * 8;
    short8 bb;
#pragma unroll
    for (int j = 0; j < 8; ++j) {
      int kc = min(kbase + j, 999);
      bb[j] = bfs(centers[(size_t)kc * 2048 + n]);
    }
    acc0 = MFMA(a0, bb, acc0);
    acc1 = MFMA(a1, bb, acc1);
  }
  float* P = ws + WS_P4 + ((size_t)ksplit * 2048 + n) * 68;
  *(f32x4*)(P + m0 + lk * 4) = acc0;
  *(f32x4*)(P + m0 + 16 + lk * 4) = acc1;
}

// ---- K6: reduce P4 + fuse: fast out, x_new bf16, ||x_new||^2 partials
__global__ __launch_bounds__(256) void k6(const float* __restrict__ x,
                                          float* __restrict__ out,
                                          float* __restrict__ ws) {
  __shared__ float T[64][65];
  int blk = blockIdx.x, t = threadIdx.x, l = t & 63, w = t >> 6;
  int d0 = blk * 64;
  const size_t KS = (size_t)2048 * 68;
  for (int dl = w; dl < 64; dl += 4) {
    const float* P = ws + WS_P4 + (size_t)(d0 + dl) * 68;
    T[dl][l] = P[l] + P[KS + l] + P[2*KS + l] + P[3*KS + l];
  }
  __syncthreads();
  const unsigned short* sel = (const unsigned short*)(ws + WS_SEL);
  unsigned short* xnb = (unsigned short*)(ws + WS_XNB);
  for (int r = 0; r < 16; ++r) {
    int b = w * 16 + r;
    float cc = T[l][b];
    float sv = bf2f(sel[(size_t)b * 2048 + d0 + l]);
    float xv = x[(size_t)b * 2048 + d0 + l];
    float fast = sv * cc;
    out[195072 + (size_t)b * 2048 + d0 + l] = fast;
    float xn = ws[WS_CONF + b] * (xv + fast);
    xnb[(size_t)b * 2048 + d0 + l] = (unsigned short)bfs(xn);
    float sq = xn * xn;
#pragma unroll
    for (int o = 32; o; o >>= 1) sq += __shfl_xor(sq, o);
    if (l == 0) ws[WS_XN2P + blk * 64 + b] = sq;
  }
}

// ---- K7: G5 = x_new @ cosw^T + ||w||^2 partials; grid 128 = 32 x 4
__global__ __launch_bounds__(256) void k7(const float* __restrict__ cosw,
                                          float* __restrict__ ws) {
  int blk = blockIdx.x, t = threadIdx.x;
  int w = t >> 6, l = t & 63;
  int colblk = blk & 31, ksplit = blk >> 5;
  int ln = l & 15, lk = l >> 4;
  int n = colblk * 32 + (w & 1) * 16 + ln;   // 0..1023
  int m0 = (w >> 1) * 32;
  int k0 = ksplit * 512;
  const float* bptr = cosw + (size_t)min(n, 999) * 2048 + k0 + lk * 8;
  const unsigned short* aptr =
      (const unsigned short*)(ws + WS_XNB) + (size_t)(m0 + ln) * 2048 + k0 + lk * 8;
  f32x4 acc0 = {0.f, 0.f, 0.f, 0.f}, acc1 = {0.f, 0.f, 0.f, 0.f};
  float sq = 0.f;
#pragma unroll 4
  for (int ks = 0; ks < 16; ++ks) {
    short8 a0 = *(const short8*)(aptr + ks * 32);
    short8 a1 = *(const short8*)(aptr + 16 * 2048 + ks * 32);
    float4 f0 = *(const float4*)(bptr + ks * 32);
    float4 f1 = *(const float4*)(bptr + ks * 32 + 4);
    sq += f0.x*f0.x + f0.y*f0.y + f0.z*f0.z + f0.w*f0.w
        + f1.x*f1.x + f1.y*f1.y + f1.z*f1.z + f1.w*f1.w;
    short8 bb;
    bb[0] = bfs(f0.x); bb[1] = bfs(f0.y); bb[2] = bfs(f0.z); bb[3] = bfs(f0.w);
    bb[4] = bfs(f1.x); bb[5] = bfs(f1.y); bb[6] = bfs(f1.z); bb[7] = bfs(f1.w);
    acc0 = MFMA(a0, bb, acc0);
    acc1 = MFMA(a1, bb, acc1);
  }
  float* P = ws + WS_P5 + ((size_t)ksplit * 1024 + n) * 68;
  *(f32x4*)(P + m0 + lk * 4) = acc0;
  *(f32x4*)(P + m0 + 16 + lk * 4) = acc1;
  sq += __shfl_xor(sq, 16);
  sq += __shfl_xor(sq, 32);
  if (w < 2 && l < 16) P[64] = sq;
}

// ---- K8: reduce P5 + cosnorm epilogue -> logits (transposed coalesced write)
__global__ __launch_bounds__(256) void k8(float* __restrict__ out,
                                          const float* __restrict__ ws) {
  __shared__ float tile[64][65];
  __shared__ float nr[64];
  int blk = blockIdx.x, t = threadIdx.x, l = t & 63, w = t >> 6;
  int c0 = blk * 64;
  const size_t KS = (size_t)1024 * 68;
  if (t < 64) {
    float s = 0.f;
    for (int i = 0; i < 32; ++i) s += ws[WS_XN2P + i * 64 + t];
    nr[t] = sqrtf(s);
  }
  __syncthreads();
  for (int cl = w; cl < 64; cl += 4) {
    int c = c0 + cl;
    const float* P = ws + WS_P5 + (size_t)c * 68;
    float v = P[l] + P[KS + l] + P[2*KS + l] + P[3*KS + l];
    float w2 = P[64] + P[KS + 64] + P[2*KS + 64] + P[3*KS + 64];
    tile[cl][l] = 16.0f * v * rsqrtf(w2) / (1.0f + nr[l]);
  }
  __syncthreads();
  for (int r = 0; r < 16; ++r) {
    int b = w * 16 + r;
    int c = c0 + l;
    if (c < 1000) out[(size_t)b * 1000 + c] = tile[l][b];
  }
}

extern "C" void kernel_launch(void* const* d_in, const int* in_sizes, int n_in,
                              void* d_out, int out_size, void* d_ws, size_t ws_size,
                              hipStream_t stream) {
  const float* x       = (const float*)d_in[0];
  const float* centers = (const float*)d_in[2];
  const float* fcw     = (const float*)d_in[4];
  const float* fcb     = (const float*)d_in[5];
  const float* fc1w    = (const float*)d_in[6];
  const float* fc1b    = (const float*)d_in[7];
  const float* cosw    = (const float*)d_in[8];
  float* out = (float*)d_out;
  float* ws  = (float*)d_ws;

  hipLaunchKernelGGL(k1, dim3(64),  dim3(256), 0, stream, x, out, ws);
  hipLaunchKernelGGL(k2, dim3(512), dim3(256), 0, stream, centers, fc1w, fcw, ws);
  hipLaunchKernelGGL(k3, dim3(64),  dim3(256), 0, stream, fc1b, fcb, ws);
  hipLaunchKernelGGL(k4, dim3(16),  dim3(256), 0, stream, ws);
  hipLaunchKernelGGL(k5, dim3(256), dim3(256), 0, stream, centers, ws);
  hipLaunchKernelGGL(k6, dim3(32),  dim3(256), 0, stream, x, out, ws);
  hipLaunchKernelGGL(k7, dim3(128), dim3(256), 0, stream, cosw, ws);
  hipLaunchKernelGGL(k8, dim3(16),  dim3(256), 0, stream, out, ws);
}

// Round 6
// 79.072 us; speedup vs baseline: 2.4391x; 1.0045x over previous
//
#include <hip/hip_runtime.h>
#include <hip/hip_bf16.h>
#include <math.h>

typedef __attribute__((ext_vector_type(8))) short short8;
typedef __attribute__((ext_vector_type(4))) float f32x4;

#define MFMA(a, b, c) __builtin_amdgcn_mfma_f32_16x16x32_bf16(a, b, c, 0, 0, 0)

// ws layout (float offsets)
enum : int {
  WS_XB   = 0,        // [64][2048] bf16 (ushort view)           65536 floats
  WS_X2   = 65536,    // [64] f32 row sumsq of x
  WS_D2MIN= 65600,    // [64] uint bits
  WS_CONF = 65664,    // [64]
  WS_P123 = 65728,    // [4][4096][68] f32 partials (+[64]=sumsq) 1114112
  WS_L1   = 1179840,  // [64][1024] f32 row-major logits_stage1
  WS_PROB = 1245376,  // [64][1024] bf16 (ushort view)
  WS_SEL  = 1278144,  // [64][2048] bf16 (ushort view)
  WS_P4   = 1343680,  // [4][2048][68] f32 partials               557056
  WS_XNB  = 1900736,  // [64][2048] bf16 (ushort view)
  WS_XN2P = 1966272,  // [32][64] f32 partials of ||x_new||^2
  WS_P5   = 1968320,  // [4][1024][68] f32 partials (+sumsq)      278528
};

__device__ inline short bfs(float f) {
  __hip_bfloat16 h = __float2bfloat16(f);
  return __builtin_bit_cast(short, h);
}
__device__ inline float bf2f(unsigned short u) {
  return __uint_as_float((unsigned)u << 16);
}

// ---- K1: x -> bf16, x row sumsq, slow_feature out, d2min init
__global__ __launch_bounds__(256) void k1(const float* __restrict__ x,
                                          float* __restrict__ out,
                                          float* __restrict__ ws) {
  __shared__ float red[4];
  int b = blockIdx.x, t = threadIdx.x;
  int l = t & 63, w = t >> 6;
  const float* xr = x + (size_t)b * 2048 + t * 8;
  float4 f0 = *(const float4*)(xr);
  float4 f1 = *(const float4*)(xr + 4);
  short8 h;
  h[0] = bfs(f0.x); h[1] = bfs(f0.y); h[2] = bfs(f0.z); h[3] = bfs(f0.w);
  h[4] = bfs(f1.x); h[5] = bfs(f1.y); h[6] = bfs(f1.z); h[7] = bfs(f1.w);
  *(short8*)((unsigned short*)(ws + WS_XB) + (size_t)b * 2048 + t * 8) = h;
  *(float4*)(out + 64000 + (size_t)b * 2048 + t * 8) = f0;
  *(float4*)(out + 64000 + (size_t)b * 2048 + t * 8 + 4) = f1;
  float s = f0.x*f0.x + f0.y*f0.y + f0.z*f0.z + f0.w*f0.w
          + f1.x*f1.x + f1.y*f1.y + f1.z*f1.z + f1.w*f1.w;
#pragma unroll
  for (int o = 32; o; o >>= 1) s += __shfl_xor(s, o);
  if (l == 0) red[w] = s;
  __syncthreads();
  if (t == 0) ws[WS_X2 + b] = red[0] + red[1] + red[2] + red[3];
  if (b == 0 && t < 64) ((unsigned*)(ws + WS_D2MIN))[t] = 0x7f800000u;  // +inf
}

// ---- K2: fused G1/G2/G3 = x @ [centers; fc1w; fcw]^T via MFMA, split-K=4
// grid 512 = 128 colblks x 4 ksplit; 4 waves: (w&1)=col half, (w>>1)=m half
__global__ __launch_bounds__(256) void k2(const float* __restrict__ centers,
                                          const float* __restrict__ fc1w,
                                          const float* __restrict__ fcw,
                                          float* __restrict__ ws) {
  int blk = blockIdx.x, t = threadIdx.x;
  int w = t >> 6, l = t & 63;
  int colblk = blk & 127, ksplit = blk >> 7;
  int ln = l & 15, lk = l >> 4;
  int n = colblk * 32 + (w & 1) * 16 + ln;   // 0..4095
  int m0 = (w >> 1) * 32;
  int k0 = ksplit * 512;
  const float* brow;
  if (n < 1024)      brow = centers + (size_t)min(n, 999) * 2048;
  else if (n < 2048) brow = fc1w + (size_t)min(n - 1024, 999) * 2048;
  else               brow = fcw + (size_t)(n - 2048) * 2048;
  const float* bptr = brow + k0 + lk * 8;
  const unsigned short* aptr =
      (const unsigned short*)(ws + WS_XB) + (size_t)(m0 + ln) * 2048 + k0 + lk * 8;
  f32x4 acc0 = {0.f, 0.f, 0.f, 0.f}, acc1 = {0.f, 0.f, 0.f, 0.f};
  float sq = 0.f;
#pragma unroll 4
  for (int ks = 0; ks < 16; ++ks) {
    short8 a0 = *(const short8*)(aptr + ks * 32);
    short8 a1 = *(const short8*)(aptr + 16 * 2048 + ks * 32);
    float4 f0 = *(const float4*)(bptr + ks * 32);
    float4 f1 = *(const float4*)(bptr + ks * 32 + 4);
    sq += f0.x*f0.x + f0.y*f0.y + f0.z*f0.z + f0.w*f0.w
        + f1.x*f1.x + f1.y*f1.y + f1.z*f1.z + f1.w*f1.w;
    short8 bb;
    bb[0] = bfs(f0.x); bb[1] = bfs(f0.y); bb[2] = bfs(f0.z); bb[3] = bfs(f0.w);
    bb[4] = bfs(f1.x); bb[5] = bfs(f1.y); bb[6] = bfs(f1.z); bb[7] = bfs(f1.w);
    acc0 = MFMA(a0, bb, acc0);
    acc1 = MFMA(a1, bb, acc1);
  }
  float* P = ws + WS_P123 + ((size_t)ksplit * 4096 + n) * 68;
  *(f32x4*)(P + m0 + lk * 4) = acc0;
  *(f32x4*)(P + m0 + 16 + lk * 4) = acc1;
  sq += __shfl_xor(sq, 16);
  sq += __shfl_xor(sq, 32);
  if (w < 2 && l < 16) P[64] = sq;   // per-col ||w||^2 partial
}

// ---- K3: reduce P123 -> d2min (seg A) / L1 (seg B) / SEL=tanh (seg C)
__global__ __launch_bounds__(256) void k3(const float* __restrict__ fc1b,
                                          const float* __restrict__ fcb,
                                          float* __restrict__ ws) {
  __shared__ float tile[64][65];
  __shared__ float red[4][64];
  int blk = blockIdx.x, t = threadIdx.x;
  int l = t & 63, w = t >> 6;
  int n0 = blk * 64;
  const size_t KS = (size_t)4096 * 68;
  float x2 = ws[WS_X2 + l];
  float tmin = 3.0e38f;
  for (int nl = w; nl < 64; nl += 4) {
    int n = n0 + nl;
    const float* P = ws + WS_P123 + (size_t)n * 68;
    float v = P[l] + P[KS + l] + P[2*KS + l] + P[3*KS + l];
    if (n < 1024) {
      if (n < 1000) {
        float c2 = P[64] + P[KS+64] + P[2*KS+64] + P[3*KS+64];
        float d2 = fmaxf(x2 - 2.f * v + c2, 0.f);
        tmin = fminf(tmin, d2);
      }
    } else if (n < 2048) {
      int c = n - 1024;
      tile[nl][l] = (c < 1000) ? v + fc1b[c] : 0.f;
    } else {
      tile[nl][l] = tanhf(v + fcb[n - 2048]);
    }
  }
  if (n0 < 1024) {
    red[w][l] = tmin;
    __syncthreads();
    if (t < 64) {
      float m = fminf(fminf(red[0][t], red[1][t]), fminf(red[2][t], red[3][t]));
      atomicMin((unsigned*)(ws + WS_D2MIN) + t, __float_as_uint(m));
    }
  } else if (n0 < 2048) {
    __syncthreads();
    int c0 = n0 - 1024;
    for (int r = 0; r < 16; ++r) {
      int m = w * 16 + r;
      ws[WS_L1 + (size_t)m * 1024 + c0 + l] = tile[l][m];
    }
  } else {
    __syncthreads();
    int d0 = n0 - 2048;
    unsigned short* sel = (unsigned short*)(ws + WS_SEL);
    for (int r = 0; r < 16; ++r) {
      int m = w * 16 + r;
      sel[(size_t)m * 2048 + d0 + l] = (unsigned short)bfs(tile[l][m]);
    }
  }
}

// ---- K4: confidence + row softmax -> PROB bf16 (wave per row)
__global__ __launch_bounds__(256) void k4(float* __restrict__ ws) {
  int t = threadIdx.x, l = t & 63, w = t >> 6;
  int b = blockIdx.x * 4 + w;
  if (blockIdx.x == 0 && t < 64) {
    float d2 = __uint_as_float(((unsigned*)(ws + WS_D2MIN))[t]);
    ws[WS_CONF + t] = 10.0f / sqrtf(d2);
  }
  const float* L = ws + WS_L1 + (size_t)b * 1024;
  float vals[16];
  float m = -3.0e38f;
#pragma unroll
  for (int i = 0; i < 16; ++i) {
    int c = i * 64 + l;
    float v = (c < 1000) ? L[c] : -3.0e38f;
    vals[i] = v;
    m = fmaxf(m, v);
  }
#pragma unroll
  for (int o = 32; o; o >>= 1) m = fmaxf(m, __shfl_xor(m, o));
  float s = 0.f;
#pragma unroll
  for (int i = 0; i < 16; ++i) {
    float e = (vals[i] > -1.0e37f) ? __expf(vals[i] - m) : 0.f;
    vals[i] = e;
    s += e;
  }
#pragma unroll
  for (int o = 32; o; o >>= 1) s += __shfl_xor(s, o);
  float inv = 1.0f / s;
  unsigned short* pb = (unsigned short*)(ws + WS_PROB) + (size_t)b * 1024;
#pragma unroll
  for (int i = 0; i < 16; ++i) pb[i * 64 + l] = (unsigned short)bfs(vals[i] * inv);
}

// ---- K5: G4 = prob @ centers (B is non-transposed: B[k][n]=centers[c][d])
// grid 256 = 64 colblks x 4 ksplit (K=1024 padded; prob[c>=1000]=0)
__global__ __launch_bounds__(256) void k5(const float* __restrict__ centers,
                                          float* __restrict__ ws) {
  int blk = blockIdx.x, t = threadIdx.x;
  int w = t >> 6, l = t & 63;
  int colblk = blk & 63, ksplit = blk >> 6;
  int ln = l & 15, lk = l >> 4;
  int n = colblk * 32 + (w & 1) * 16 + ln;   // d: 0..2047
  int m0 = (w >> 1) * 32;
  int k0 = ksplit * 256;
  const unsigned short* aptr =
      (const unsigned short*)(ws + WS_PROB) + (size_t)(m0 + ln) * 1024 + k0 + lk * 8;
  f32x4 acc0 = {0.f, 0.f, 0.f, 0.f}, acc1 = {0.f, 0.f, 0.f, 0.f};
  for (int ks = 0; ks < 8; ++ks) {
    short8 a0 = *(const short8*)(aptr + ks * 32);
    short8 a1 = *(const short8*)(aptr + 16 * 1024 + ks * 32);
    int kbase = k0 + ks * 32 + lk * 8;
    short8 bb;
#pragma unroll
    for (int j = 0; j < 8; ++j) {
      int kc = min(kbase + j, 999);
      bb[j] = bfs(centers[(size_t)kc * 2048 + n]);
    }
    acc0 = MFMA(a0, bb, acc0);
    acc1 = MFMA(a1, bb, acc1);
  }
  float* P = ws + WS_P4 + ((size_t)ksplit * 2048 + n) * 68;
  *(f32x4*)(P + m0 + lk * 4) = acc0;
  *(f32x4*)(P + m0 + 16 + lk * 4) = acc1;
}

// ---- K6: reduce P4 + fuse: fast out, x_new bf16, ||x_new||^2 partials
__global__ __launch_bounds__(256) void k6(const float* __restrict__ x,
                                          float* __restrict__ out,
                                          float* __restrict__ ws) {
  __shared__ float T[64][65];
  int blk = blockIdx.x, t = threadIdx.x, l = t & 63, w = t >> 6;
  int d0 = blk * 64;
  const size_t KS = (size_t)2048 * 68;
  for (int dl = w; dl < 64; dl += 4) {
    const float* P = ws + WS_P4 + (size_t)(d0 + dl) * 68;
    T[dl][l] = P[l] + P[KS + l] + P[2*KS + l] + P[3*KS + l];
  }
  __syncthreads();
  const unsigned short* sel = (const unsigned short*)(ws + WS_SEL);
  unsigned short* xnb = (unsigned short*)(ws + WS_XNB);
  for (int r = 0; r < 16; ++r) {
    int b = w * 16 + r;
    float cc = T[l][b];
    float sv = bf2f(sel[(size_t)b * 2048 + d0 + l]);
    float xv = x[(size_t)b * 2048 + d0 + l];
    float fast = sv * cc;
    out[195072 + (size_t)b * 2048 + d0 + l] = fast;
    float xn = ws[WS_CONF + b] * (xv + fast);
    xnb[(size_t)b * 2048 + d0 + l] = (unsigned short)bfs(xn);
    float sq = xn * xn;
#pragma unroll
    for (int o = 32; o; o >>= 1) sq += __shfl_xor(sq, o);
    if (l == 0) ws[WS_XN2P + blk * 64 + b] = sq;
  }
}

// ---- K7: G5 = x_new @ cosw^T + ||w||^2 partials; grid 128 = 32 x 4
__global__ __launch_bounds__(256) void k7(const float* __restrict__ cosw,
                                          float* __restrict__ ws) {
  int blk = blockIdx.x, t = threadIdx.x;
  int w = t >> 6, l = t & 63;
  int colblk = blk & 31, ksplit = blk >> 5;
  int ln = l & 15, lk = l >> 4;
  int n = colblk * 32 + (w & 1) * 16 + ln;   // 0..1023
  int m0 = (w >> 1) * 32;
  int k0 = ksplit * 512;
  const float* bptr = cosw + (size_t)min(n, 999) * 2048 + k0 + lk * 8;
  const unsigned short* aptr =
      (const unsigned short*)(ws + WS_XNB) + (size_t)(m0 + ln) * 2048 + k0 + lk * 8;
  f32x4 acc0 = {0.f, 0.f, 0.f, 0.f}, acc1 = {0.f, 0.f, 0.f, 0.f};
  float sq = 0.f;
#pragma unroll 4
  for (int ks = 0; ks < 16; ++ks) {
    short8 a0 = *(const short8*)(aptr + ks * 32);
    short8 a1 = *(const short8*)(aptr + 16 * 2048 + ks * 32);
    float4 f0 = *(const float4*)(bptr + ks * 32);
    float4 f1 = *(const float4*)(bptr + ks * 32 + 4);
    sq += f0.x*f0.x + f0.y*f0.y + f0.z*f0.z + f0.w*f0.w
        + f1.x*f1.x + f1.y*f1.y + f1.z*f1.z + f1.w*f1.w;
    short8 bb;
    bb[0] = bfs(f0.x); bb[1] = bfs(f0.y); bb[2] = bfs(f0.z); bb[3] = bfs(f0.w);
    bb[4] = bfs(f1.x); bb[5] = bfs(f1.y); bb[6] = bfs(f1.z); bb[7] = bfs(f1.w);
    acc0 = MFMA(a0, bb, acc0);
    acc1 = MFMA(a1, bb, acc1);
  }
  float* P = ws + WS_P5 + ((size_t)ksplit * 1024 + n) * 68;
  *(f32x4*)(P + m0 + lk * 4) = acc0;
  *(f32x4*)(P + m0 + 16 + lk * 4) = acc1;
  sq += __shfl_xor(sq, 16);
  sq += __shfl_xor(sq, 32);
  if (w < 2 && l < 16) P[64] = sq;
}

// ---- K8: reduce P5 + cosnorm epilogue -> logits (transposed coalesced write)
__global__ __launch_bounds__(256) void k8(float* __restrict__ out,
                                          const float* __restrict__ ws) {
  __shared__ float tile[64][65];
  __shared__ float nr[64];
  int blk = blockIdx.x, t = threadIdx.x, l = t & 63, w = t >> 6;
  int c0 = blk * 64;
  const size_t KS = (size_t)1024 * 68;
  if (t < 64) {
    float s = 0.f;
    for (int i = 0; i < 32; ++i) s += ws[WS_XN2P + i * 64 + t];
    nr[t] = sqrtf(s);
  }
  __syncthreads();
  for (int cl = w; cl < 64; cl += 4) {
    int c = c0 + cl;
    const float* P = ws + WS_P5 + (size_t)c * 68;
    float v = P[l] + P[KS + l] + P[2*KS + l] + P[3*KS + l];
    float w2 = P[64] + P[KS + 64] + P[2*KS + 64] + P[3*KS + 64];
    tile[cl][l] = 16.0f * v * rsqrtf(w2) / (1.0f + nr[l]);
  }
  __syncthreads();
  for (int r = 0; r < 16; ++r) {
    int b = w * 16 + r;
    int c = c0 + l;
    if (c < 1000) out[(size_t)b * 1000 + c] = tile[l][b];
  }
}

extern "C" void kernel_launch(void* const* d_in, const int* in_sizes, int n_in,
                              void* d_out, int out_size, void* d_ws, size_t ws_size,
                              hipStream_t stream) {
  const float* x       = (const float*)d_in[0];
  const float* centers = (const float*)d_in[2];
  const float* fcw     = (const float*)d_in[4];
  const float* fcb     = (const float*)d_in[5];
  const float* fc1w    = (const float*)d_in[6];
  const float* fc1b    = (const float*)d_in[7];
  const float* cosw    = (const float*)d_in[8];
  float* out = (float*)d_out;
  float* ws  = (float*)d_ws;

  hipLaunchKernelGGL(k1, dim3(64),  dim3(256), 0, stream, x, out, ws);
  hipLaunchKernelGGL(k2, dim3(512), dim3(256), 0, stream, centers, fc1w, fcw, ws);
  hipLaunchKernelGGL(k3, dim3(64),  dim3(256), 0, stream, fc1b, fcb, ws);
  hipLaunchKernelGGL(k4, dim3(16),  dim3(256), 0, stream, ws);
  hipLaunchKernelGGL(k5, dim3(256), dim3(256), 0, stream, centers, ws);
  hipLaunchKernelGGL(k6, dim3(32),  dim3(256), 0, stream, x, out, ws);
  hipLaunchKernelGGL(k7, dim3(128), dim3(256), 0, stream, cosw, ws);
  hipLaunchKernelGGL(k8, dim3(16),  dim3(256), 0, stream, out, ws);
}